// Round 1
// baseline (1271.095 us; speedup 1.0000x reference)
//
#include <hip/hip_runtime.h>
#include <hip/hip_bf16.h>
#include <math.h>

// UltraMemLayerV2: BS=4096 HID=2048 KDIM=256 KEY_NUM=512 HEAD=2 RANK=2 KNN=16 VDIM=512
// Selection path (q-GEMM, LN, a-GEMM, cand scores) in f64 arithmetic / f32 storage:
// topk boundary swaps cost ~5e-3 absmax (>> 7.5e-4 threshold), so score noise must be ~1e-8.
// Value path (gather, combine, final GEMM) in f32: continuous, error ~1e-7 << threshold.

#define GCONST 0.10881882041201557   // 256^-0.4 (f64)

__device__ __forceinline__ double wred_sum(double v) {
#pragma unroll
  for (int off = 32; off; off >>= 1) v += __shfl_xor(v, off);
  return v;
}

// ---------------- f64-accum GEMM: C(f32)[M][N] = A(f32)[M][K] * B(f32)[N][K]^T --------
// 64x64 tile, BK=16, 256 threads, 4x4 per thread. Dims must divide tiles (they do here).
__global__ __launch_bounds__(256) void dgemm64(const float* __restrict__ A, int lda,
                                               const float* __restrict__ B, int ldb,
                                               float* __restrict__ C, int ldc, int K) {
  __shared__ double As[16][64];
  __shared__ double Bs[16][64];
  const int tid = threadIdx.x;
  const int m0 = blockIdx.y * 64, n0 = blockIdx.x * 64;
  const int lr = tid >> 2, lc = (tid & 3) * 4;
  const int tx = tid & 15, ty = tid >> 4;
  const float* Ap = A + (size_t)(m0 + lr) * lda + lc;
  const float* Bp = B + (size_t)(n0 + lr) * ldb + lc;
  double acc[4][4] = {};
  for (int k0 = 0; k0 < K; k0 += 16) {
    float4 a4 = *(const float4*)(Ap + k0);
    float4 b4 = *(const float4*)(Bp + k0);
    __syncthreads();
    As[lc + 0][lr] = (double)a4.x; As[lc + 1][lr] = (double)a4.y;
    As[lc + 2][lr] = (double)a4.z; As[lc + 3][lr] = (double)a4.w;
    Bs[lc + 0][lr] = (double)b4.x; Bs[lc + 1][lr] = (double)b4.y;
    Bs[lc + 2][lr] = (double)b4.z; Bs[lc + 3][lr] = (double)b4.w;
    __syncthreads();
#pragma unroll
    for (int kk = 0; kk < 16; ++kk) {
      double av[4], bv[4];
#pragma unroll
      for (int i = 0; i < 4; ++i) av[i] = As[kk][ty * 4 + i];
#pragma unroll
      for (int i = 0; i < 4; ++i) bv[i] = Bs[kk][tx * 4 + i];
#pragma unroll
      for (int i = 0; i < 4; ++i)
#pragma unroll
        for (int j = 0; j < 4; ++j) acc[i][j] = fma(av[i], bv[j], acc[i][j]);
    }
  }
#pragma unroll
  for (int i = 0; i < 4; ++i) {
    float4 o = make_float4((float)acc[i][0], (float)acc[i][1], (float)acc[i][2], (float)acc[i][3]);
    *(float4*)(C + (size_t)(m0 + ty * 4 + i) * ldc + n0 + tx * 4) = o;
  }
}

// ---------------- f32 GEMM (final projection): C[M][N] = A[M][K] * B[N][K]^T ----------
// 128x128 tile, BK=8, 256 threads, 8x8 per thread.
__global__ __launch_bounds__(256) void sgemm128(const float* __restrict__ A, int lda,
                                                const float* __restrict__ B, int ldb,
                                                float* __restrict__ C, int ldc, int K) {
  __shared__ float As[8][128];
  __shared__ float Bs[8][128];
  const int tid = threadIdx.x;
  const int m0 = blockIdx.y * 128, n0 = blockIdx.x * 128;
  const int lr = tid >> 1, lc = (tid & 1) * 4;
  const int tx = tid & 15, ty = tid >> 4;
  const float* Ap = A + (size_t)(m0 + lr) * lda + lc;
  const float* Bp = B + (size_t)(n0 + lr) * ldb + lc;
  float acc[8][8] = {};
  for (int k0 = 0; k0 < K; k0 += 8) {
    float4 a4 = *(const float4*)(Ap + k0);
    float4 b4 = *(const float4*)(Bp + k0);
    __syncthreads();
    As[lc + 0][lr] = a4.x; As[lc + 1][lr] = a4.y; As[lc + 2][lr] = a4.z; As[lc + 3][lr] = a4.w;
    Bs[lc + 0][lr] = b4.x; Bs[lc + 1][lr] = b4.y; Bs[lc + 2][lr] = b4.z; Bs[lc + 3][lr] = b4.w;
    __syncthreads();
#pragma unroll
    for (int kk = 0; kk < 8; ++kk) {
      float av[8], bv[8];
      *(float4*)&av[0] = *(const float4*)&As[kk][ty * 8];
      *(float4*)&av[4] = *(const float4*)&As[kk][ty * 8 + 4];
      *(float4*)&bv[0] = *(const float4*)&Bs[kk][tx * 8];
      *(float4*)&bv[4] = *(const float4*)&Bs[kk][tx * 8 + 4];
#pragma unroll
      for (int i = 0; i < 8; ++i)
#pragma unroll
        for (int j = 0; j < 8; ++j) acc[i][j] = fmaf(av[i], bv[j], acc[i][j]);
    }
  }
#pragma unroll
  for (int i = 0; i < 8; ++i) {
    float* Cp = C + (size_t)(m0 + ty * 8 + i) * ldc + n0 + tx * 8;
    *(float4*)Cp       = make_float4(acc[i][0], acc[i][1], acc[i][2], acc[i][3]);
    *(float4*)(Cp + 4) = make_float4(acc[i][4], acc[i][5], acc[i][6], acc[i][7]);
  }
}

// ---------------- LayerNorm of q halves: one wave per (b, half) ----------------------
__global__ __launch_bounds__(64) void ln_q_kernel(const float* __restrict__ q,
                                                  float* __restrict__ qn) {
  const int bx = blockIdx.x;          // b*2 + half; q row stride 512 -> offset bx*256
  const int lane = threadIdx.x;
  const float* src = q + (size_t)bx * 256;
  float4 v = *(const float4*)(src + lane * 4);
  double e0 = (double)v.x, e1 = (double)v.y, e2 = (double)v.z, e3 = (double)v.w;
  double s = e0 + e1 + e2 + e3;
  double s2 = e0 * e0 + e1 * e1 + e2 * e2 + e3 * e3;
  s = wred_sum(s); s2 = wred_sum(s2);
  double m = s * (1.0 / 256.0);
  double var = s2 * (1.0 / 256.0) - m * m;
  double sc = GCONST / sqrt(var + 1e-5);
  float4 o = make_float4((float)((e0 - m) * sc), (float)((e1 - m) * sc),
                         (float)((e2 - m) * sc), (float)((e3 - m) * sc));
  *(float4*)(qn + (size_t)bx * 256 + lane * 4) = o;
}

// -------- LayerNorm of keys over kdim + pre-contraction ku = kn . (u or v) -----------
// keys flat [h][s][n][k][r] (r innermost). kn out: [s][h][n][r][k]. ku out: [s][h][n][k].
__global__ __launch_bounds__(64) void ln_keys_kernel(const float* __restrict__ keys,
                                                     const float* __restrict__ u,
                                                     const float* __restrict__ vv,
                                                     float* __restrict__ kn,
                                                     float* __restrict__ ku) {
  const int bx = blockIdx.x;          // (h*2 + s)*512 + n
  const int lane = threadIdx.x;
  const int h = bx >> 10, s = (bx >> 9) & 1, n = bx & 511;
  const float* src = keys + (size_t)bx * 512;
  float4 v0 = *(const float4*)(src + lane * 8);
  float4 v1 = *(const float4*)(src + lane * 8 + 4);
  double e0 = (double)v0.x, e1 = (double)v0.y, e2 = (double)v0.z, e3 = (double)v0.w;
  double f0 = (double)v1.x, f1 = (double)v1.y, f2 = (double)v1.z, f3 = (double)v1.w;
  double s0 = e0 + e2 + f0 + f2;          // r=0 terms (k = 4l .. 4l+3)
  double s1 = e1 + e3 + f1 + f3;          // r=1 terms
  double q0 = e0 * e0 + e2 * e2 + f0 * f0 + f2 * f2;
  double q1 = e1 * e1 + e3 * e3 + f1 * f1 + f3 * f3;
  s0 = wred_sum(s0); s1 = wred_sum(s1); q0 = wred_sum(q0); q1 = wred_sum(q1);
  double m0 = s0 * (1.0 / 256.0), m1 = s1 * (1.0 / 256.0);
  double c0 = GCONST / sqrt(q0 * (1.0 / 256.0) - m0 * m0 + 1e-5);
  double c1 = GCONST / sqrt(q1 * (1.0 / 256.0) - m1 * m1 + 1e-5);
  double r0[4] = {(e0 - m0) * c0, (e2 - m0) * c0, (f0 - m0) * c0, (f2 - m0) * c0};
  double r1[4] = {(e1 - m1) * c1, (e3 - m1) * c1, (f1 - m1) * c1, (f3 - m1) * c1};
  size_t ob = ((size_t)((s * 2 + h) << 9) + n) * 512;
  *(float4*)(kn + ob + lane * 4)       = make_float4((float)r0[0], (float)r0[1], (float)r0[2], (float)r0[3]);
  *(float4*)(kn + ob + 256 + lane * 4) = make_float4((float)r1[0], (float)r1[1], (float)r1[2], (float)r1[3]);
  const float* uvp = s ? vv : u;
  double w0 = (double)uvp[h * 2 + 0], w1 = (double)uvp[h * 2 + 1];
  float4 kuo = make_float4((float)(r0[0] * w0 + r1[0] * w1), (float)(r0[1] * w0 + r1[1] * w1),
                           (float)(r0[2] * w0 + r1[2] * w1), (float)(r0[3] * w0 + r1[3] * w1));
  *(float4*)(ku + ((size_t)((s * 2 + h) << 9) + n) * 256 + lane * 4) = kuo;
}

// ---------------- top-16 of 512 rank-1 scores: one wave per (side,b,h) ---------------
__global__ __launch_bounds__(64) void topk_a_kernel(const float* __restrict__ a,
                                                    int* __restrict__ idxo) {
  const int bx = blockIdx.x;          // (side*4096 + b)*2 + h
  const int lane = threadIdx.x;
  const float* row = a + (size_t)(bx >> 1) * 1024 + (size_t)(bx & 1) * 512;
  float val[8];
#pragma unroll
  for (int j = 0; j < 8; ++j) val[j] = row[lane + 64 * j];
  int keep = 0;
  for (int it = 0; it < 16; ++it) {
    float bv = val[0]; int bn = lane;
#pragma unroll
    for (int j = 1; j < 8; ++j) {
      int n = lane + 64 * j;
      if (val[j] > bv) { bv = val[j]; bn = n; }
    }
#pragma unroll
    for (int off = 32; off; off >>= 1) {
      float ov = __shfl_xor(bv, off); int on = __shfl_xor(bn, off);
      if (ov > bv || (ov == bv && on < bn)) { bv = ov; bn = on; }
    }
    if (lane == it) keep = bn;
#pragma unroll
    for (int j = 0; j < 8; ++j) if (lane + 64 * j == bn) val[j] = -INFINITY;
  }
  if (lane < 16) idxo[(size_t)bx * 16 + lane] = keep;
}

// ------- candidate grid (f64): s1g/s2g dots, tucker scores, top-16, softmax, vidx -----
__global__ __launch_bounds__(64) void cand_kernel(const float* __restrict__ qn,
                                                  const float* __restrict__ kn,
                                                  const float* __restrict__ core0,
                                                  const float* __restrict__ core1,
                                                  const int* __restrict__ idx1,
                                                  const int* __restrict__ shuf,
                                                  int* __restrict__ vidx,
                                                  float* __restrict__ wgt) {
  const int bx = blockIdx.x;          // b*2 + h
  const int b = bx >> 1, h = bx & 1;
  const int lane = threadIdx.x;
  __shared__ int i1s[16], i2s[16];
  __shared__ double sg[2][16][2];
  __shared__ double t1[16][2];
  if (lane < 16) i1s[lane] = idx1[(size_t)bx * 16 + lane];
  else if (lane < 32) i2s[lane - 16] = idx1[(size_t)(8192 + bx) * 16 + (lane - 16)];
  const double C00 = (double)core0[h * 4 + 0] + (double)core1[h * 4 + 0];
  const double C01 = (double)core0[h * 4 + 1] + (double)core1[h * 4 + 1];
  const double C10 = (double)core0[h * 4 + 2] + (double)core1[h * 4 + 2];
  const double C11 = (double)core0[h * 4 + 3] + (double)core1[h * 4 + 3];
  __syncthreads();
  {
    const int side = lane >> 5;
    const int li = (lane >> 1) & 15;
    const int r = lane & 1;
    const int idx = (side == 0) ? i1s[li] : i2s[li];
    const float* kr = kn + ((((size_t)(side * 2 + h) << 9) + idx) * 2 + r) * 256;
    const float* qv = qn + (size_t)b * 512 + (side << 8);
    double acc = 0.0;
    for (int k = 0; k < 256; k += 4) {
      float4 k4 = *(const float4*)(kr + k);
      float4 q4 = *(const float4*)(qv + k);
      acc = fma((double)k4.x, (double)q4.x, acc);
      acc = fma((double)k4.y, (double)q4.y, acc);
      acc = fma((double)k4.z, (double)q4.z, acc);
      acc = fma((double)k4.w, (double)q4.w, acc);
    }
    sg[side][li][r] = acc;
  }
  __syncthreads();
  if (lane < 32) {
    const int i = lane >> 1, sp = lane & 1;
    t1[i][sp] = sg[0][i][0] * (sp ? C01 : C00) + sg[0][i][1] * (sp ? C11 : C10);
  }
  __syncthreads();
  double cv[4];
#pragma unroll
  for (int t = 0; t < 4; ++t) {
    const int p = lane * 4 + t;
    cv[t] = t1[p >> 4][0] * sg[1][p & 15][0] + t1[p >> 4][1] * sg[1][p & 15][1];
  }
  double rsc = -INFINITY; int rp = 0;
  for (int it = 0; it < 16; ++it) {
    double bv = cv[0]; int bp = lane * 4;
#pragma unroll
    for (int t = 1; t < 4; ++t) if (cv[t] > bv) { bv = cv[t]; bp = lane * 4 + t; }
#pragma unroll
    for (int off = 32; off; off >>= 1) {
      double ov = __shfl_xor(bv, off); int op = __shfl_xor(bp, off);
      if (ov > bv || (ov == bv && op < bp)) { bv = ov; bp = op; }
    }
    if (lane == it) { rsc = bv; rp = bp; }
#pragma unroll
    for (int t = 0; t < 4; ++t) if (lane * 4 + t == bp) cv[t] = -INFINITY;
  }
  const double mx = __shfl(rsc, 0);
  double e = (lane < 16) ? exp(rsc - mx) : 0.0;
  double ssum = e;
#pragma unroll
  for (int off = 8; off; off >>= 1) ssum += __shfl_xor(ssum, off);
  if (lane < 16) {
    const int ii = rp >> 4, jj = rp & 15;
    const int vslot = shuf[i1s[ii] * 512 + i2s[jj]];
    vidx[(size_t)bx * 16 + lane] = vslot;
    wgt[(size_t)bx * 16 + lane] = (float)(e / ssum);
  }
}

// ---------------- weighted sparse gather: out_v[b] = sum_j w_j * values[vidx_j] ------
__global__ __launch_bounds__(128) void gather_kernel(const float* __restrict__ values,
                                                     const int* __restrict__ vidx,
                                                     const float* __restrict__ wgt,
                                                     float* __restrict__ out_v) {
  const int b = blockIdx.x, tid = threadIdx.x;
  __shared__ float ws[32];
  __shared__ int vs[32];
  if (tid < 32) { ws[tid] = wgt[b * 32 + tid]; vs[tid] = vidx[b * 32 + tid]; }
  __syncthreads();
  const float4* V = (const float4*)values;
  float4 acc = make_float4(0.f, 0.f, 0.f, 0.f);
  for (int j = 0; j < 32; ++j) {
    const float w = ws[j];
    float4 r = V[(size_t)vs[j] * 128 + tid];
    acc.x = fmaf(w, r.x, acc.x); acc.y = fmaf(w, r.y, acc.y);
    acc.z = fmaf(w, r.z, acc.z); acc.w = fmaf(w, r.w, acc.w);
  }
  ((float4*)out_v)[(size_t)b * 128 + tid] = acc;
}

extern "C" void kernel_launch(void* const* d_in, const int* in_sizes, int n_in,
                              void* d_out, int out_size, void* d_ws, size_t ws_size,
                              hipStream_t stream) {
  (void)in_sizes; (void)n_in; (void)out_size; (void)ws_size;
  const float* x     = (const float*)d_in[0];
  const float* qw    = (const float*)d_in[1];
  const float* keys  = (const float*)d_in[2];
  const float* core0 = (const float*)d_in[3];
  const float* core1 = (const float*)d_in[4];
  const float* u     = (const float*)d_in[5];
  const float* v     = (const float*)d_in[6];
  const float* values= (const float*)d_in[7];
  const float* vpw   = (const float*)d_in[8];
  const int*   shuf  = (const int*)d_in[9];
  float* out = (float*)d_out;

  float* ws   = (float*)d_ws;
  float* q    = ws;                       // [4096][512]            2,097,152
  float* qn   = q    + 2097152;           // [4096][512]            2,097,152
  float* kn   = qn   + 2097152;           // [2][2][512][2][256]    1,048,576
  float* ku   = kn   + 1048576;           // [2][2][512][256]         524,288
  float* a    = ku   + 524288;            // [2][4096][1024]        8,388,608
  int*   idx1 = (int*)(a + 8388608);      // [2][4096][2][16]         262,144
  int*   vidx = idx1 + 262144;            // [4096][2][16]            131,072
  float* wgt  = (float*)(vidx + 131072);  // [4096][2][16]            131,072
  float* outv = wgt  + 131072;            // [4096][512]            2,097,152

  // 1. q = x @ q_proj_w^T   (f64 accum)
  dgemm64<<<dim3(512 / 64, 4096 / 64), 256, 0, stream>>>(x, 2048, qw, 2048, q, 512, 2048);
  // 2. per-half LayerNorm of q
  ln_q_kernel<<<8192, 64, 0, stream>>>(q, qn);
  // 3. key LayerNorm + ku pre-contraction
  ln_keys_kernel<<<2048, 64, 0, stream>>>(keys, u, v, kn, ku);
  // 4. rank-1 approx scores a = qn_half @ ku^T per side (f64 accum)
  dgemm64<<<dim3(1024 / 64, 4096 / 64), 256, 0, stream>>>(qn, 512, ku, 256, a, 1024, 256);
  dgemm64<<<dim3(1024 / 64, 4096 / 64), 256, 0, stream>>>(qn + 256, 512, ku + 262144, 256,
                                                          a + 4194304, 1024, 256);
  // 5. top-16 per (side,b,h)
  topk_a_kernel<<<16384, 64, 0, stream>>>(a, idx1);
  // 6. exact tucker scores on 16x16 grid, final top-16, softmax, value-slot lookup
  cand_kernel<<<8192, 64, 0, stream>>>(qn, kn, core0, core1, idx1, shuf, vidx, wgt);
  // 7. weighted sparse gather from values
  gather_kernel<<<4096, 128, 0, stream>>>(values, vidx, wgt, outv);
  // 8. out = out_v @ values_proj_w^T (f32)
  sgemm128<<<dim3(2048 / 128, 4096 / 128), 256, 0, stream>>>(outv, 512, vpw, 512, out, 2048, 512);
}